// Round 8
// baseline (2308.447 us; speedup 1.0000x reference)
//
#include <hip/hip_runtime.h>

#define B 8
#define N 16384
#define C_IN 32
#define P 1024

typedef float v2f __attribute__((ext_vector_type(2)));
typedef unsigned long long ull;

// ---------------------------------------------------------------------------
// FPS (FROZEN at R7 form, ~1810us): one block per batch, 1024 threads,
// 16 points/thread as 8 index-pairs; pk math; DPP value-max; key-atomic
// argmax; single barrier/iter. R5/R6/R7 all land 1810-1830 -> floor for this
// structure; counters can't see the residual. Do not touch.
// ---------------------------------------------------------------------------
#define R8(OP) OP(0) OP(1) OP(2) OP(3) OP(4) OP(5) OP(6) OP(7)

__device__ __forceinline__ v2f pk_add(v2f a, v2f b) {
  v2f d; asm("v_pk_add_f32 %0, %1, %2" : "=v"(d) : "v"(a), "v"(b)); return d;
}
__device__ __forceinline__ v2f pk_mul(v2f a, v2f b) {
  v2f d; asm("v_pk_mul_f32 %0, %1, %2" : "=v"(d) : "v"(a), "v"(b)); return d;
}
__device__ __forceinline__ float negf(float x) {
  return __int_as_float(__float_as_int(x) ^ 0x80000000);
}

template <int CTRL>
__device__ __forceinline__ float dpp_fmax(float v) {
  float o = __int_as_float(__builtin_amdgcn_update_dpp(
      __float_as_int(v), __float_as_int(v), CTRL, 0xF, 0xF, false));
  return fmaxf(v, o);
}

__global__ __launch_bounds__(1024)
void fps_kernel(const float* __restrict__ xyz, float* __restrict__ new_xyz)
{
  __shared__ __align__(16) float sx[N];      // 64 KiB
  __shared__ __align__(16) float sy[N];      // 64 KiB
  __shared__ ull slot[2];                    // argmax key, parity-alternating

  const int b = blockIdx.x;
  const int t = threadIdx.x;
  const float* xb = xyz + (size_t)b * (N * 3);

  if (t == 0) { slot[0] = ~0ull; slot[1] = ~0ull; }

  // pair j (j=0..7) = points {n0, n0+1}, n0 = 4t + 4096*(j>>1) + 2*(j&1)
#define FPS_DECL(j) v2f pzp##j, dmp##j; dmp##j.x = 1e10f; dmp##j.y = 1e10f;
  R8(FPS_DECL)
#define FPS_LOADP(j) {                                                         \
    const int n0 = (t << 2) + ((j >> 1) << 12) + ((j & 1) << 1);               \
    const float2 ld0 = *(const float2*)&xb[(size_t)n0 * 3 + 0]; /* x0,y0 */    \
    const float2 ld1 = *(const float2*)&xb[(size_t)n0 * 3 + 2]; /* z0,x1 */    \
    const float2 ld2 = *(const float2*)&xb[(size_t)n0 * 3 + 4]; /* y1,z1 */    \
    sx[n0]     = ld0.x;  sy[n0]     = ld0.y;                                   \
    sx[n0 + 1] = ld1.y;  sy[n0 + 1] = ld2.x;                                   \
    pzp##j.x   = ld1.x;  pzp##j.y   = ld2.y;                                   \
    asm volatile("" : "+v"(pzp##j)); }
  R8(FPS_LOADP)

  float cz = xb[2];                 // z of point 0
  __syncthreads();
  float cx = sx[0], cy = sy[0];
  int sel = 0, msel = 0;

  for (int iter = 0; iter < P; ++iter) {
    msel = (t == iter) ? sel : msel;
    if (iter == P - 1) break;

    v2f cxx, cyy, czz;
    { float v = negf(cx); cxx.x = v; cxx.y = v; }
    { float v = negf(cy); cyy.x = v; cyy.y = v; }
    { float v = negf(cz); czz.x = v; czz.y = v; }

    // ---- xy phase: sq_j = dx*dx + dy*dy for all 8 pairs (no cz dep) ----
    v2f sq0, sq1, sq2, sq3, sq4, sq5, sq6, sq7;
#define FPS_XY(i, ja, jb) {                                                    \
      const int n0 = (t << 2) + ((i) << 12);                                   \
      v2f xl = *(const v2f*)&sx[n0];  v2f xh = *(const v2f*)&sx[n0 + 2];       \
      v2f yl = *(const v2f*)&sy[n0];  v2f yh = *(const v2f*)&sy[n0 + 2];       \
      v2f dxl = pk_add(xl, cxx), dyl = pk_add(yl, cyy);                        \
      v2f dxh = pk_add(xh, cxx), dyh = pk_add(yh, cyy);                        \
      sq##ja = pk_add(pk_mul(dxl, dxl), pk_mul(dyl, dyl));                     \
      sq##jb = pk_add(pk_mul(dxh, dxh), pk_mul(dyh, dyh)); }
    FPS_XY(0, 0, 1)
    FPS_XY(1, 2, 3)
    FPS_XY(2, 4, 5)
    FPS_XY(3, 6, 7)

    // ---- z phase + dmin + per-thread argmax ----
    float bestv = -1.0f;
    int   s = 0;
#define FPS_Z(j) {                                                             \
      v2f dz = pk_add(pzp##j, czz);                                            \
      v2f dd = pk_add(sq##j, pk_mul(dz, dz));                                  \
      dmp##j.x = fminf(dmp##j.x, dd.x);                                        \
      dmp##j.y = fminf(dmp##j.y, dd.y);                                        \
      bool b0 = dmp##j.x > bestv;                                              \
      bestv = b0 ? dmp##j.x : bestv;  s = b0 ? (2 * (j))     : s;              \
      bool b1 = dmp##j.y > bestv;                                              \
      bestv = b1 ? dmp##j.y : bestv;  s = b1 ? (2 * (j) + 1) : s; }
    R8(FPS_Z)

    // ---- value-only wave max: 6 DPP levels -> lane 63, readlane ----
    float wm = bestv;
    wm = dpp_fmax<0xB1>(wm);
    wm = dpp_fmax<0x4E>(wm);
    wm = dpp_fmax<0x141>(wm);
    wm = dpp_fmax<0x140>(wm);
    wm = dpp_fmax<0x142>(wm);
    wm = dpp_fmax<0x143>(wm);
    const float wmax = __int_as_float(
        __builtin_amdgcn_readlane(__float_as_int(wm), 63));

    if (bestv == wmax) {
      int nn = (t << 2) + ((s & 12) << 10) + (s & 3);        // 14 bits
      unsigned inv = ~__float_as_uint(bestv);                // desc in val
      ull key = ((ull)(unsigned)(P - 1 - iter) << 46) |
                ((ull)inv << 14) | (ull)(unsigned)nn;
      atomicMin(&slot[iter & 1], key);
    }
    __syncthreads();

    ull k = slot[iter & 1];
    sel = __builtin_amdgcn_readfirstlane((int)((unsigned)k & 0x3FFFu));
    cx = sx[sel];
    cy = sy[sel];
    cz = xb[(size_t)sel * 3 + 2];
  }

  {
    const int n = msel;
    size_t o = ((size_t)b * P + t) * 3;
    new_xyz[o + 0] = sx[n];
    new_xyz[o + 1] = sy[n];
    new_xyz[o + 2] = xb[(size_t)n * 3 + 2];
  }
#undef FPS_DECL
#undef FPS_LOADP
#undef FPS_XY
#undef FPS_Z
}

// ---------------------------------------------------------------------------
// Feature transpose: feats (B,32,N) -> ftr (B,N,32), LDS 32x65 tile,
// coalesced loads and stores. Makes the mlp gather contiguous (R8).
// ---------------------------------------------------------------------------
__global__ __launch_bounds__(256) void tr_kernel(
    const float* __restrict__ feats, float* __restrict__ ftr)
{
  __shared__ float tile[32][65];
  const int tid = threadIdx.x;
  const int b  = blockIdx.x >> 8;            // N/64 = 256 tiles per batch
  const int n0 = (blockIdx.x & 255) << 6;
  const float* fb = feats + (size_t)b * (C_IN * N);

  const int c  = tid >> 3;
  const int nn = (tid & 7) << 3;
  const float* src = fb + (size_t)c * N + n0 + nn;
  const float4 a0 = *(const float4*)(src);
  const float4 a1 = *(const float4*)(src + 4);
  tile[c][nn + 0] = a0.x; tile[c][nn + 1] = a0.y;
  tile[c][nn + 2] = a0.z; tile[c][nn + 3] = a0.w;
  tile[c][nn + 4] = a1.x; tile[c][nn + 5] = a1.y;
  tile[c][nn + 6] = a1.z; tile[c][nn + 7] = a1.w;
  __syncthreads();

  const int n  = tid >> 2;
  const int c0 = (tid & 3) << 3;
  float4 o0, o1;
  o0.x = tile[c0 + 0][n]; o0.y = tile[c0 + 1][n];
  o0.z = tile[c0 + 2][n]; o0.w = tile[c0 + 3][n];
  o1.x = tile[c0 + 4][n]; o1.y = tile[c0 + 5][n];
  o1.z = tile[c0 + 6][n]; o1.w = tile[c0 + 7][n];
  float4* dst = (float4*)(ftr + ((size_t)b * N + n0 + n) * 32 + c0);
  dst[0] = o0;
  dst[1] = o1;
}

// ---------------------------------------------------------------------------
// Ball query (unchanged, passing). One wave per (b,p); gemm-form dist2
// bitwise; first-nsample-in-index-order via ballot + prefix popcount.
// ---------------------------------------------------------------------------
__global__ __launch_bounds__(256) void ballq_kernel(
    const float* __restrict__ xyz, const float* __restrict__ new_xyz,
    int* __restrict__ idx0, int* __restrict__ idx1)
{
  const int wid  = blockIdx.x * 4 + (threadIdx.x >> 6);
  const int lane = threadIdx.x & 63;
  const int b = wid >> 10;
  const int p = wid & (P - 1);
  const float* xb = xyz + (size_t)b * (N * 3);
  const size_t bp = (size_t)b * P + p;
  const float cx = new_xyz[bp * 3 + 0];
  const float cy = new_xyz[bp * 3 + 1];
  const float cz = new_xyz[bp * 3 + 2];
  const float qv = __fadd_rn(__fadd_rn(__fmul_rn(cx, cx), __fmul_rn(cy, cy)),
                             __fmul_rn(cz, cz));
  int* __restrict__ o0 = idx0 + bp * 16;
  int* __restrict__ o1 = idx1 + bp * 32;

  int c0 = 0, c1 = 0, f0 = 0, f1 = 0;
  const unsigned long long below = (1ull << lane) - 1ull;

  for (int base = 0; base < N; base += 64) {
    int n = base + lane;
    float x = xb[n * 3 + 0], y = xb[n * 3 + 1], z = xb[n * 3 + 2];
    float xxv = __fadd_rn(__fadd_rn(__fmul_rn(x, x), __fmul_rn(y, y)),
                          __fmul_rn(z, z));
    float dot = __fadd_rn(__fadd_rn(__fmul_rn(cx, x), __fmul_rn(cy, y)),
                          __fmul_rn(cz, z));
    float d2 = __fsub_rn(__fadd_rn(qv, xxv), __fmul_rn(2.0f, dot));
    unsigned long long m0 = __ballot(d2 < 0.25f);
    unsigned long long m1 = __ballot(d2 < 1.0f);
    if (c0 == 0 && m0) f0 = base + __builtin_ctzll(m0);
    if (c1 == 0 && m1) f1 = base + __builtin_ctzll(m1);
    if ((m0 >> lane) & 1ull) {
      int pos = c0 + (int)__builtin_popcountll(m0 & below);
      if (pos < 16) o0[pos] = n;
    }
    if ((m1 >> lane) & 1ull) {
      int pos = c1 + (int)__builtin_popcountll(m1 & below);
      if (pos < 32) o1[pos] = n;
    }
    c0 = min(16, c0 + (int)__builtin_popcountll(m0));
    c1 = min(32, c1 + (int)__builtin_popcountll(m1));
    if (c0 >= 16 && c1 >= 32) break;
  }
  for (int s = c0 + lane; s < 16; s += 64) o0[s] = f0;
  for (int s = c1 + lane; s < 32; s += 64) o1[s] = f1;
}

// ---------------------------------------------------------------------------
// Fused grouping + conv1 + conv2 + max. R8 changes:
//  - features read from transposed ftr (B,N,32): one float4 per thread per
//    point (2 cache lines/sample instead of 32 scattered dwords)
//  - wl2 staged via contiguous float4 reads into padded [C1][C2+1] rows
//    (kills 32-way staging-write conflict and layer-2 read conflicts)
//  - v_pk_fma_f32 over the o-pair (layer1) / s-pair (layer2) dimension;
//    the per-(o,s) c-chain order is unchanged -> bitwise-identical output.
// Layouts xs[35][S], o1s[C1][S] and thread mappings unchanged (conflict-free
// as measured). out layout: (B,192,P) at d_out + B*P*3.
// ---------------------------------------------------------------------------
template <int S, int C1, int C2, int CH_OFF>
__global__ __launch_bounds__(256) void mlp_kernel(
    const float* __restrict__ xyz, const float* __restrict__ ftr,
    const float* __restrict__ new_xyz, const int* __restrict__ idx,
    const float* __restrict__ w1, const float* __restrict__ s1,
    const float* __restrict__ b1, const float* __restrict__ w2,
    const float* __restrict__ s2, const float* __restrict__ b2,
    float* __restrict__ out)
{
  static_assert((C1 * S) % 512 == 0 && (C2 * S) % 512 == 0, "mapping");
  __shared__ float wl1[35][C1];      // wl1[c][o] = w1[o][c]
  __shared__ float wl2[C1][C2 + 1];  // wl2[c][o] = w2[o][c], padded row
  __shared__ float sb1[2][C1];
  __shared__ float sb2[2][C2];
  __shared__ float xs[35][S];
  __shared__ float o1s[C1][S];
  __shared__ float pm[256];

  const int tid = threadIdx.x;
  for (int i = tid; i < 35 * C1; i += 256) {
    int o = i % C1, c = i / C1;
    wl1[c][o] = w1[o * 35 + c];
  }
  // contiguous float4 reads of w2; padded-row writes are ~2-way (free)
  for (int i = tid; i < (C1 * C2) / 4; i += 256) {
    const float4 v = *(const float4*)&w2[i * 4];
    const int o = (i * 4) / C1, c = (i * 4) % C1;
    wl2[c + 0][o] = v.x; wl2[c + 1][o] = v.y;
    wl2[c + 2][o] = v.z; wl2[c + 3][o] = v.w;
  }
  if (tid < C1) { sb1[0][tid] = s1[tid]; sb1[1][tid] = b1[tid]; }
  if (tid < C2) { sb2[0][tid] = s2[tid]; sb2[1][tid] = b2[tid]; }

  const int b  = blockIdx.x / (P / 8);
  const int p0 = (blockIdx.x % (P / 8)) * 8;
  const float* xb = xyz + (size_t)b * (N * 3);
  const float* fb = ftr + (size_t)b * N * 32;   // (N,32) transposed features
  __syncthreads();

  for (int pi = 0; pi < 8; ++pi) {
    const int p = p0 + pi;
    const size_t bp = (size_t)b * P + p;
    const int* ip = idx + bp * S;
    const float cx = new_xyz[bp * 3 + 0];
    const float cy = new_xyz[bp * 3 + 1];
    const float cz = new_xyz[bp * 3 + 2];
    // xyz-diff channels: one thread per sample
    for (int s2 = tid; s2 < S; s2 += 256) {
      const int n = ip[s2];
      xs[0][s2] = xb[n * 3 + 0] - cx;
      xs[1][s2] = xb[n * 3 + 1] - cy;
      xs[2][s2] = xb[n * 3 + 2] - cz;
    }
    // feature channels: 8 threads per sample, one float4 each (contiguous)
    for (int i = tid; i < S * 8; i += 256) {
      const int s = i >> 3, q = i & 7;
      const int n = ip[s];
      const float4 v = *(const float4*)&fb[(size_t)n * 32 + q * 4];
      const int c = 3 + q * 4;
      xs[c + 0][s] = v.x; xs[c + 1][s] = v.y;
      xs[c + 2][s] = v.z; xs[c + 3][s] = v.w;
    }
    __syncthreads();
    // layer 1: acc chains over c in order (bitwise == previous version);
    // pk pairs span the o dimension.
    {
      constexpr int OPT  = (C1 * S) / 256;
      constexpr int OPT2 = OPT / 2;
      const int s  = tid % S;
      const int ob = (tid / S) * OPT;
      v2f acc[OPT2];
#pragma unroll
      for (int m = 0; m < OPT2; ++m) { acc[m].x = 0.0f; acc[m].y = 0.0f; }
      for (int c = 0; c < 35; ++c) {
        const float xv = xs[c][s];
        v2f xv2; xv2.x = xv; xv2.y = xv;
#pragma unroll
        for (int m = 0; m < OPT2; ++m) {
          const v2f w = *(const v2f*)&wl1[c][ob + 2 * m];
          asm("v_pk_fma_f32 %0, %1, %2, %0"
              : "+v"(acc[m]) : "v"(xv2), "v"(w));
        }
      }
#pragma unroll
      for (int m = 0; m < OPT2; ++m) {
        const int o0i = ob + 2 * m, o1i = ob + 2 * m + 1;
        float v0 = fmaf(acc[m].x, sb1[0][o0i], sb1[1][o0i]);
        float v1 = fmaf(acc[m].y, sb1[0][o1i], sb1[1][o1i]);
        o1s[o0i][s] = fmaxf(v0, 0.0f);
        o1s[o1i][s] = fmaxf(v1, 0.0f);
      }
    }
    __syncthreads();
    // layer 2 + max over s; pk pairs span the s dimension.
    {
      constexpr int NS  = (C2 * S) / 256;
      constexpr int NS2 = NS / 2;
      const int o2 = tid % C2;
      const int sb = (tid / C2) * NS;
      v2f acc[NS2];
#pragma unroll
      for (int m = 0; m < NS2; ++m) { acc[m].x = 0.0f; acc[m].y = 0.0f; }
      for (int c = 0; c < C1; ++c) {
        const float wv = wl2[c][o2];
        v2f wv2; wv2.x = wv; wv2.y = wv;
#pragma unroll
        for (int m = 0; m < NS2; ++m) {
          const v2f ov = *(const v2f*)&o1s[c][sb + 2 * m];
          asm("v_pk_fma_f32 %0, %1, %2, %0"
              : "+v"(acc[m]) : "v"(wv2), "v"(ov));
        }
      }
      const float scale = sb2[0][o2], bias = sb2[1][o2];
      float m2 = 0.0f;  // relu floor: max over relu(v) == max(0, max v)
#pragma unroll
      for (int m = 0; m < NS2; ++m) {
        m2 = fmaxf(m2, fmaf(acc[m].x, scale, bias));
        m2 = fmaxf(m2, fmaf(acc[m].y, scale, bias));
      }
      pm[tid] = m2;
      __syncthreads();
      if (tid < C2) {
        float mm = pm[tid];
#pragma unroll
        for (int g = 1; g < 256 / C2; ++g) mm = fmaxf(mm, pm[tid + g * C2]);
        out[((size_t)b * 192 + CH_OFF + tid) * P + p] = mm;
      }
    }
    __syncthreads();
  }
}

extern "C" void kernel_launch(void* const* d_in, const int* in_sizes, int n_in,
                              void* d_out, int out_size, void* d_ws, size_t ws_size,
                              hipStream_t stream) {
  const float* xyz   = (const float*)d_in[0];
  const float* feats = (const float*)d_in[1];
  const float* w0_0 = (const float*)d_in[2];
  const float* s0_0 = (const float*)d_in[3];
  const float* b0_0 = (const float*)d_in[4];
  const float* w0_1 = (const float*)d_in[5];
  const float* s0_1 = (const float*)d_in[6];
  const float* b0_1 = (const float*)d_in[7];
  const float* w1_0 = (const float*)d_in[8];
  const float* s1_0 = (const float*)d_in[9];
  const float* b1_0 = (const float*)d_in[10];
  const float* w1_1 = (const float*)d_in[11];
  const float* s1_1 = (const float*)d_in[12];
  const float* b1_1 = (const float*)d_in[13];

  float* out      = (float*)d_out;
  float* new_xyz  = out;                      // (B,P,3)
  float* feat_out = out + (size_t)B * P * 3;  // (B,192,P)

  char* w = (char*)d_ws;
  float* ftr = (float*)w; w += (size_t)B * N * 32 * sizeof(float);  // 16 MB
  int* idx0 = (int*)w; w += (size_t)B * P * 16 * sizeof(int);
  int* idx1 = (int*)w; w += (size_t)B * P * 32 * sizeof(int);

  tr_kernel<<<dim3(B * (N / 64)), dim3(256), 0, stream>>>(feats, ftr);
  fps_kernel<<<dim3(B), dim3(1024), 0, stream>>>(xyz, new_xyz);
  ballq_kernel<<<dim3(B * P / 4), dim3(256), 0, stream>>>(xyz, new_xyz, idx0, idx1);
  mlp_kernel<16, 32, 64, 0><<<dim3(B * P / 8), dim3(256), 0, stream>>>(
      xyz, ftr, new_xyz, idx0, w0_0, s0_0, b0_0, w0_1, s0_1, b0_1, feat_out);
  mlp_kernel<32, 64, 128, 64><<<dim3(B * P / 8), dim3(256), 0, stream>>>(
      xyz, ftr, new_xyz, idx1, w1_0, s1_0, b1_0, w1_1, s1_1, b1_1, feat_out);
}

// Round 9
// 2192.556 us; speedup vs baseline: 1.0529x; 1.0529x over previous
//
#include <hip/hip_runtime.h>

#define B 8
#define N 16384
#define C_IN 32
#define P 1024

typedef float v2f __attribute__((ext_vector_type(2)));
typedef unsigned long long ull;

// ---------------------------------------------------------------------------
// Fused FPS + prep. Blocks 0..7: FPS (FROZEN R7 logic, ~1810us, one block per
// batch). Blocks 8..519: prep = feature transpose (B,32,N)->(B,N,32) and
// xyz SoA split x[],y[],z[] (for ballq's dense float4 loads). Prep has no
// dependency on FPS (different in/out) -> runs concurrently on idle CUs,
// fully hidden under FPS; stream order guarantees completion before ballq.
// LDS: union (fps: sx/sy/slot = 128KB+16; prep: 32x257 tile = 33KB).
// ---------------------------------------------------------------------------
#define R8(OP) OP(0) OP(1) OP(2) OP(3) OP(4) OP(5) OP(6) OP(7)

__device__ __forceinline__ v2f pk_add(v2f a, v2f b) {
  v2f d; asm("v_pk_add_f32 %0, %1, %2" : "=v"(d) : "v"(a), "v"(b)); return d;
}
__device__ __forceinline__ v2f pk_mul(v2f a, v2f b) {
  v2f d; asm("v_pk_mul_f32 %0, %1, %2" : "=v"(d) : "v"(a), "v"(b)); return d;
}
__device__ __forceinline__ float negf(float x) {
  return __int_as_float(__float_as_int(x) ^ 0x80000000);
}

template <int CTRL>
__device__ __forceinline__ float dpp_fmax(float v) {
  float o = __int_as_float(__builtin_amdgcn_update_dpp(
      __float_as_int(v), __float_as_int(v), CTRL, 0xF, 0xF, false));
  return fmaxf(v, o);
}

__global__ __launch_bounds__(1024)
void fps_prep_kernel(const float* __restrict__ xyz,
                     const float* __restrict__ feats,
                     float* __restrict__ new_xyz,
                     float* __restrict__ ftr,
                     float* __restrict__ sox, float* __restrict__ soy,
                     float* __restrict__ soz)
{
  __shared__ __align__(16) char smem[131088];
  const int t = threadIdx.x;

  if (blockIdx.x >= 8) {
    // ---------------- prep path: transpose + SoA ----------------
    const int pid   = blockIdx.x - 8;          // 0..511
    const int pb    = pid >> 6;                // batch
    const int n0    = (pid & 63) << 8;         // 256-point chunk
    const float* fb = feats + (size_t)pb * (C_IN * N);
    const float* xb = xyz + (size_t)pb * (N * 3);
    float (*tile)[257] = (float(*)[257])smem;

    // load 32 x 256 chunk of feats (coalesced float4)
    {
      const int c  = t >> 5;            // 0..31
      const int nn = (t & 31) << 3;     // 0..248
      const float* src = fb + (size_t)c * N + n0 + nn;
      const float4 a0 = *(const float4*)(src);
      const float4 a1 = *(const float4*)(src + 4);
      tile[c][nn + 0] = a0.x; tile[c][nn + 1] = a0.y;
      tile[c][nn + 2] = a0.z; tile[c][nn + 3] = a0.w;
      tile[c][nn + 4] = a1.x; tile[c][nn + 5] = a1.y;
      tile[c][nn + 6] = a1.z; tile[c][nn + 7] = a1.w;
    }
    // SoA xyz split for this chunk (independent of tile)
    if (t < 256) {
      const int n = n0 + t;
      const size_t o = (size_t)pb * N + n;
      sox[o] = xb[(size_t)n * 3 + 0];
      soy[o] = xb[(size_t)n * 3 + 1];
      soz[o] = xb[(size_t)n * 3 + 2];
    }
    __syncthreads();
    // store transposed (coalesced float4 rows of 32)
    {
      const int n  = t >> 2;            // 0..255
      const int c0 = (t & 3) << 3;      // 0,8,16,24
      float4 o0, o1;
      o0.x = tile[c0 + 0][n]; o0.y = tile[c0 + 1][n];
      o0.z = tile[c0 + 2][n]; o0.w = tile[c0 + 3][n];
      o1.x = tile[c0 + 4][n]; o1.y = tile[c0 + 5][n];
      o1.z = tile[c0 + 6][n]; o1.w = tile[c0 + 7][n];
      float4* dst = (float4*)(ftr + ((size_t)pb * N + n0 + n) * 32 + c0);
      dst[0] = o0;
      dst[1] = o1;
    }
    return;
  }

  // ---------------- FPS path (frozen R7 logic) ----------------
  float* sx = (float*)smem;                    // N floats
  float* sy = sx + N;                          // N floats
  ull*  slot = (ull*)(smem + 2 * N * sizeof(float));

  const int b = blockIdx.x;
  const float* xb = xyz + (size_t)b * (N * 3);

  if (t == 0) { slot[0] = ~0ull; slot[1] = ~0ull; }

  // pair j (j=0..7) = points {n0, n0+1}, n0 = 4t + 4096*(j>>1) + 2*(j&1)
#define FPS_DECL(j) v2f pzp##j, dmp##j; dmp##j.x = 1e10f; dmp##j.y = 1e10f;
  R8(FPS_DECL)
#define FPS_LOADP(j) {                                                         \
    const int n0 = (t << 2) + ((j >> 1) << 12) + ((j & 1) << 1);               \
    const float2 ld0 = *(const float2*)&xb[(size_t)n0 * 3 + 0]; /* x0,y0 */    \
    const float2 ld1 = *(const float2*)&xb[(size_t)n0 * 3 + 2]; /* z0,x1 */    \
    const float2 ld2 = *(const float2*)&xb[(size_t)n0 * 3 + 4]; /* y1,z1 */    \
    sx[n0]     = ld0.x;  sy[n0]     = ld0.y;                                   \
    sx[n0 + 1] = ld1.y;  sy[n0 + 1] = ld2.x;                                   \
    pzp##j.x   = ld1.x;  pzp##j.y   = ld2.y;                                   \
    asm volatile("" : "+v"(pzp##j)); }
  R8(FPS_LOADP)

  float cz = xb[2];                 // z of point 0
  __syncthreads();
  float cx = sx[0], cy = sy[0];
  int sel = 0, msel = 0;

  for (int iter = 0; iter < P; ++iter) {
    msel = (t == iter) ? sel : msel;
    if (iter == P - 1) break;

    v2f cxx, cyy, czz;
    { float v = negf(cx); cxx.x = v; cxx.y = v; }
    { float v = negf(cy); cyy.x = v; cyy.y = v; }
    { float v = negf(cz); czz.x = v; czz.y = v; }

    // ---- xy phase: sq_j = dx*dx + dy*dy for all 8 pairs (no cz dep) ----
    v2f sq0, sq1, sq2, sq3, sq4, sq5, sq6, sq7;
#define FPS_XY(i, ja, jb) {                                                    \
      const int n0 = (t << 2) + ((i) << 12);                                   \
      v2f xl = *(const v2f*)&sx[n0];  v2f xh = *(const v2f*)&sx[n0 + 2];       \
      v2f yl = *(const v2f*)&sy[n0];  v2f yh = *(const v2f*)&sy[n0 + 2];       \
      v2f dxl = pk_add(xl, cxx), dyl = pk_add(yl, cyy);                        \
      v2f dxh = pk_add(xh, cxx), dyh = pk_add(yh, cyy);                        \
      sq##ja = pk_add(pk_mul(dxl, dxl), pk_mul(dyl, dyl));                     \
      sq##jb = pk_add(pk_mul(dxh, dxh), pk_mul(dyh, dyh)); }
    FPS_XY(0, 0, 1)
    FPS_XY(1, 2, 3)
    FPS_XY(2, 4, 5)
    FPS_XY(3, 6, 7)

    // ---- z phase + dmin + per-thread argmax ----
    float bestv = -1.0f;
    int   s = 0;
#define FPS_Z(j) {                                                             \
      v2f dz = pk_add(pzp##j, czz);                                            \
      v2f dd = pk_add(sq##j, pk_mul(dz, dz));                                  \
      dmp##j.x = fminf(dmp##j.x, dd.x);                                        \
      dmp##j.y = fminf(dmp##j.y, dd.y);                                        \
      bool b0 = dmp##j.x > bestv;                                              \
      bestv = b0 ? dmp##j.x : bestv;  s = b0 ? (2 * (j))     : s;              \
      bool b1 = dmp##j.y > bestv;                                              \
      bestv = b1 ? dmp##j.y : bestv;  s = b1 ? (2 * (j) + 1) : s; }
    R8(FPS_Z)

    // ---- value-only wave max: 6 DPP levels -> lane 63, readlane ----
    float wm = bestv;
    wm = dpp_fmax<0xB1>(wm);
    wm = dpp_fmax<0x4E>(wm);
    wm = dpp_fmax<0x141>(wm);
    wm = dpp_fmax<0x140>(wm);
    wm = dpp_fmax<0x142>(wm);
    wm = dpp_fmax<0x143>(wm);
    const float wmax = __int_as_float(
        __builtin_amdgcn_readlane(__float_as_int(wm), 63));

    if (bestv == wmax) {
      int nn = (t << 2) + ((s & 12) << 10) + (s & 3);        // 14 bits
      unsigned inv = ~__float_as_uint(bestv);                // desc in val
      ull key = ((ull)(unsigned)(P - 1 - iter) << 46) |
                ((ull)inv << 14) | (ull)(unsigned)nn;
      atomicMin(&slot[iter & 1], key);
    }
    __syncthreads();

    ull k = slot[iter & 1];
    sel = __builtin_amdgcn_readfirstlane((int)((unsigned)k & 0x3FFFu));
    cx = sx[sel];
    cy = sy[sel];
    cz = xb[(size_t)sel * 3 + 2];
  }

  {
    const int n = msel;
    size_t o = ((size_t)b * P + t) * 3;
    new_xyz[o + 0] = sx[n];
    new_xyz[o + 1] = sy[n];
    new_xyz[o + 2] = xb[(size_t)n * 3 + 2];
  }
#undef FPS_DECL
#undef FPS_LOADP
#undef FPS_XY
#undef FPS_Z
}

// ---------------------------------------------------------------------------
// Ball query R9: SoA inputs, 4 points/lane (256 points/round/wave), dense
// float4 loads (16 lines/instr, the coalescing minimum — was ~48 with
// stride-12 dwords). Hit enumeration via 4 ballots + prefix popcount keeps
// EXACT first-nsample-in-ascending-index semantics; pad = first hit (0 if
// none). Distance math bitwise identical: (qv+xx) - 2*dot, all __f*_rn.
// ---------------------------------------------------------------------------
__global__ __launch_bounds__(256) void ballq_kernel(
    const float* __restrict__ sox, const float* __restrict__ soy,
    const float* __restrict__ soz, const float* __restrict__ new_xyz,
    int* __restrict__ idx0, int* __restrict__ idx1)
{
  const int wid  = blockIdx.x * 4 + (threadIdx.x >> 6);
  const int lane = threadIdx.x & 63;
  const int b = wid >> 10;
  const int p = wid & (P - 1);
  const float* X = sox + (size_t)b * N;
  const float* Y = soy + (size_t)b * N;
  const float* Z = soz + (size_t)b * N;
  const size_t bp = (size_t)b * P + p;
  const float cx = new_xyz[bp * 3 + 0];
  const float cy = new_xyz[bp * 3 + 1];
  const float cz = new_xyz[bp * 3 + 2];
  const float qv = __fadd_rn(__fadd_rn(__fmul_rn(cx, cx), __fmul_rn(cy, cy)),
                             __fmul_rn(cz, cz));
  int* __restrict__ o0 = idx0 + bp * 16;
  int* __restrict__ o1 = idx1 + bp * 32;

  int c0 = 0, c1 = 0, f0 = 0, f1 = 0;
  const ull below = (1ull << lane) - 1ull;

  for (int base = 0; base < N; base += 256) {
    const int n0 = base + (lane << 2);
    const float4 xv = *(const float4*)&X[n0];
    const float4 yv = *(const float4*)&Y[n0];
    const float4 zv = *(const float4*)&Z[n0];

    float d2[4];
#pragma unroll
    for (int e = 0; e < 4; ++e) {
      const float x = (e == 0) ? xv.x : (e == 1) ? xv.y : (e == 2) ? xv.z : xv.w;
      const float y = (e == 0) ? yv.x : (e == 1) ? yv.y : (e == 2) ? yv.z : yv.w;
      const float z = (e == 0) ? zv.x : (e == 1) ? zv.y : (e == 2) ? zv.z : zv.w;
      const float xx = __fadd_rn(__fadd_rn(__fmul_rn(x, x), __fmul_rn(y, y)),
                                 __fmul_rn(z, z));
      const float dot = __fadd_rn(__fadd_rn(__fmul_rn(cx, x), __fmul_rn(cy, y)),
                                  __fmul_rn(cz, z));
      d2[e] = __fsub_rn(__fadd_rn(qv, xx), __fmul_rn(2.0f, dot));
    }

    ull m0[4], m1[4];
#pragma unroll
    for (int e = 0; e < 4; ++e) {
      m0[e] = __ballot(d2[e] < 0.25f);
      m1[e] = __ballot(d2[e] < 1.0f);
    }

#define BQ_PROC(m, cap, oarr, cnt, fst) {                                      \
    const int tot = (int)(__builtin_popcountll(m[0]) +                         \
                          __builtin_popcountll(m[1]) +                         \
                          __builtin_popcountll(m[2]) +                         \
                          __builtin_popcountll(m[3]));                         \
    if (cnt < cap && tot) {                                                    \
      if (cnt == 0) {                                                          \
        const ull any = m[0] | m[1] | m[2] | m[3];                             \
        const int lm = __builtin_ctzll(any);                                   \
        const int em = ((m[0] >> lm) & 1ull) ? 0 :                             \
                       ((m[1] >> lm) & 1ull) ? 1 :                             \
                       ((m[2] >> lm) & 1ull) ? 2 : 3;                          \
        fst = base + (lm << 2) + em;                                           \
      }                                                                        \
      int pos = cnt + (int)(__builtin_popcountll(m[0] & below) +               \
                            __builtin_popcountll(m[1] & below) +               \
                            __builtin_popcountll(m[2] & below) +               \
                            __builtin_popcountll(m[3] & below));               \
      const bool h0 = (m[0] >> lane) & 1ull;                                   \
      const bool h1 = (m[1] >> lane) & 1ull;                                   \
      const bool h2 = (m[2] >> lane) & 1ull;                                   \
      const bool h3 = (m[3] >> lane) & 1ull;                                   \
      if (h0 && pos < cap) oarr[pos] = n0 + 0;                                 \
      pos += h0;                                                               \
      if (h1 && pos < cap) oarr[pos] = n0 + 1;                                 \
      pos += h1;                                                               \
      if (h2 && pos < cap) oarr[pos] = n0 + 2;                                 \
      pos += h2;                                                               \
      if (h3 && pos < cap) oarr[pos] = n0 + 3;                                 \
    }                                                                          \
    cnt = min(cap, cnt + tot); }

    BQ_PROC(m0, 16, o0, c0, f0)
    BQ_PROC(m1, 32, o1, c1, f1)
#undef BQ_PROC
    if (c0 >= 16 && c1 >= 32) break;
  }
  for (int s = c0 + lane; s < 16; s += 64) o0[s] = f0;
  for (int s = c1 + lane; s < 32; s += 64) o1[s] = f1;
}

// ---------------------------------------------------------------------------
// Fused grouping + conv1 + conv2 + max (R8 form, unchanged, passing):
// transposed-feature float4 gather, padded wl2, pk-fma over o/s pairs;
// per-(o,s) c-chain order unchanged -> bitwise-identical output.
// ---------------------------------------------------------------------------
template <int S, int C1, int C2, int CH_OFF>
__global__ __launch_bounds__(256) void mlp_kernel(
    const float* __restrict__ xyz, const float* __restrict__ ftr,
    const float* __restrict__ new_xyz, const int* __restrict__ idx,
    const float* __restrict__ w1, const float* __restrict__ s1,
    const float* __restrict__ b1, const float* __restrict__ w2,
    const float* __restrict__ s2, const float* __restrict__ b2,
    float* __restrict__ out)
{
  static_assert((C1 * S) % 512 == 0 && (C2 * S) % 512 == 0, "mapping");
  __shared__ float wl1[35][C1];      // wl1[c][o] = w1[o][c]
  __shared__ float wl2[C1][C2 + 1];  // wl2[c][o] = w2[o][c], padded row
  __shared__ float sb1[2][C1];
  __shared__ float sb2[2][C2];
  __shared__ float xs[35][S];
  __shared__ float o1s[C1][S];
  __shared__ float pm[256];

  const int tid = threadIdx.x;
  for (int i = tid; i < 35 * C1; i += 256) {
    int o = i % C1, c = i / C1;
    wl1[c][o] = w1[o * 35 + c];
  }
  for (int i = tid; i < (C1 * C2) / 4; i += 256) {
    const float4 v = *(const float4*)&w2[i * 4];
    const int o = (i * 4) / C1, c = (i * 4) % C1;
    wl2[c + 0][o] = v.x; wl2[c + 1][o] = v.y;
    wl2[c + 2][o] = v.z; wl2[c + 3][o] = v.w;
  }
  if (tid < C1) { sb1[0][tid] = s1[tid]; sb1[1][tid] = b1[tid]; }
  if (tid < C2) { sb2[0][tid] = s2[tid]; sb2[1][tid] = b2[tid]; }

  const int b  = blockIdx.x / (P / 8);
  const int p0 = (blockIdx.x % (P / 8)) * 8;
  const float* xb = xyz + (size_t)b * (N * 3);
  const float* fb = ftr + (size_t)b * N * 32;
  __syncthreads();

  for (int pi = 0; pi < 8; ++pi) {
    const int p = p0 + pi;
    const size_t bp = (size_t)b * P + p;
    const int* ip = idx + bp * S;
    const float cx = new_xyz[bp * 3 + 0];
    const float cy = new_xyz[bp * 3 + 1];
    const float cz = new_xyz[bp * 3 + 2];
    for (int s2i = tid; s2i < S; s2i += 256) {
      const int n = ip[s2i];
      xs[0][s2i] = xb[n * 3 + 0] - cx;
      xs[1][s2i] = xb[n * 3 + 1] - cy;
      xs[2][s2i] = xb[n * 3 + 2] - cz;
    }
    for (int i = tid; i < S * 8; i += 256) {
      const int s = i >> 3, q = i & 7;
      const int n = ip[s];
      const float4 v = *(const float4*)&fb[(size_t)n * 32 + q * 4];
      const int c = 3 + q * 4;
      xs[c + 0][s] = v.x; xs[c + 1][s] = v.y;
      xs[c + 2][s] = v.z; xs[c + 3][s] = v.w;
    }
    __syncthreads();
    {
      constexpr int OPT  = (C1 * S) / 256;
      constexpr int OPT2 = OPT / 2;
      const int s  = tid % S;
      const int ob = (tid / S) * OPT;
      v2f acc[OPT2];
#pragma unroll
      for (int m = 0; m < OPT2; ++m) { acc[m].x = 0.0f; acc[m].y = 0.0f; }
      for (int c = 0; c < 35; ++c) {
        const float xv = xs[c][s];
        v2f xv2; xv2.x = xv; xv2.y = xv;
#pragma unroll
        for (int m = 0; m < OPT2; ++m) {
          const v2f w = *(const v2f*)&wl1[c][ob + 2 * m];
          asm("v_pk_fma_f32 %0, %1, %2, %0"
              : "+v"(acc[m]) : "v"(xv2), "v"(w));
        }
      }
#pragma unroll
      for (int m = 0; m < OPT2; ++m) {
        const int o0i = ob + 2 * m, o1i = ob + 2 * m + 1;
        float v0 = fmaf(acc[m].x, sb1[0][o0i], sb1[1][o0i]);
        float v1 = fmaf(acc[m].y, sb1[0][o1i], sb1[1][o1i]);
        o1s[o0i][s] = fmaxf(v0, 0.0f);
        o1s[o1i][s] = fmaxf(v1, 0.0f);
      }
    }
    __syncthreads();
    {
      constexpr int NS  = (C2 * S) / 256;
      constexpr int NS2 = NS / 2;
      const int o2 = tid % C2;
      const int sb = (tid / C2) * NS;
      v2f acc[NS2];
#pragma unroll
      for (int m = 0; m < NS2; ++m) { acc[m].x = 0.0f; acc[m].y = 0.0f; }
      for (int c = 0; c < C1; ++c) {
        const float wv = wl2[c][o2];
        v2f wv2; wv2.x = wv; wv2.y = wv;
#pragma unroll
        for (int m = 0; m < NS2; ++m) {
          const v2f ov = *(const v2f*)&o1s[c][sb + 2 * m];
          asm("v_pk_fma_f32 %0, %1, %2, %0"
              : "+v"(acc[m]) : "v"(wv2), "v"(ov));
        }
      }
      const float scale = sb2[0][o2], bias = sb2[1][o2];
      float m2 = 0.0f;
#pragma unroll
      for (int m = 0; m < NS2; ++m) {
        m2 = fmaxf(m2, fmaf(acc[m].x, scale, bias));
        m2 = fmaxf(m2, fmaf(acc[m].y, scale, bias));
      }
      pm[tid] = m2;
      __syncthreads();
      if (tid < C2) {
        float mm = pm[tid];
#pragma unroll
        for (int g = 1; g < 256 / C2; ++g) mm = fmaxf(mm, pm[tid + g * C2]);
        out[((size_t)b * 192 + CH_OFF + tid) * P + p] = mm;
      }
    }
    __syncthreads();
  }
}

extern "C" void kernel_launch(void* const* d_in, const int* in_sizes, int n_in,
                              void* d_out, int out_size, void* d_ws, size_t ws_size,
                              hipStream_t stream) {
  const float* xyz   = (const float*)d_in[0];
  const float* feats = (const float*)d_in[1];
  const float* w0_0 = (const float*)d_in[2];
  const float* s0_0 = (const float*)d_in[3];
  const float* b0_0 = (const float*)d_in[4];
  const float* w0_1 = (const float*)d_in[5];
  const float* s0_1 = (const float*)d_in[6];
  const float* b0_1 = (const float*)d_in[7];
  const float* w1_0 = (const float*)d_in[8];
  const float* s1_0 = (const float*)d_in[9];
  const float* b1_0 = (const float*)d_in[10];
  const float* w1_1 = (const float*)d_in[11];
  const float* s1_1 = (const float*)d_in[12];
  const float* b1_1 = (const float*)d_in[13];

  float* out      = (float*)d_out;
  float* new_xyz  = out;                      // (B,P,3)
  float* feat_out = out + (size_t)B * P * 3;  // (B,192,P)

  char* w = (char*)d_ws;
  float* ftr = (float*)w; w += (size_t)B * N * 32 * sizeof(float);  // 16 MB
  float* sox = (float*)w; w += (size_t)B * N * sizeof(float);
  float* soy = (float*)w; w += (size_t)B * N * sizeof(float);
  float* soz = (float*)w; w += (size_t)B * N * sizeof(float);
  int* idx0 = (int*)w; w += (size_t)B * P * 16 * sizeof(int);
  int* idx1 = (int*)w; w += (size_t)B * P * 32 * sizeof(int);

  fps_prep_kernel<<<dim3(8 + B * (N / 256)), dim3(1024), 0, stream>>>(
      xyz, feats, new_xyz, ftr, sox, soy, soz);
  ballq_kernel<<<dim3(B * P / 4), dim3(256), 0, stream>>>(
      sox, soy, soz, new_xyz, idx0, idx1);
  mlp_kernel<16, 32, 64, 0><<<dim3(B * P / 8), dim3(256), 0, stream>>>(
      xyz, ftr, new_xyz, idx0, w0_0, s0_0, b0_0, w0_1, s0_1, b0_1, feat_out);
  mlp_kernel<32, 64, 128, 64><<<dim3(B * P / 8), dim3(256), 0, stream>>>(
      xyz, ftr, new_xyz, idx1, w1_0, s1_0, b1_0, w1_1, s1_1, b1_1, feat_out);
}